// Round 15
// baseline (332.797 us; speedup 1.0000x reference)
//
#include <hip/hip_runtime.h>
#include <cstdint>
#include <cstddef>

constexpr int HID = 128;
constexpr int LATENT = 64;
constexpr int BSHIFT = 7;           // 128 nodes per bucket
constexpr int NBUCK_MAX = 512;      // supports up to 65536 nodes
constexpr int EPB = 1024;           // edges per block in bucket passes

typedef __attribute__((ext_vector_type(8))) short short8;
typedef __attribute__((ext_vector_type(4))) float f32x4;

__device__ inline unsigned short f2bf(float f) {
    unsigned u = __float_as_uint(f);
    u += 0x7fff + ((u >> 16) & 1);          // RNE
    return (unsigned short)(u >> 16);
}
__device__ inline unsigned pack_bf16x2(float lo, float hi) {
    unsigned ulo = __float_as_uint(lo);
    unsigned uhi = __float_as_uint(hi);
    ulo += 0x7fff + ((ulo >> 16) & 1);
    uhi += 0x7fff + ((uhi >> 16) & 1);
    return (ulo >> 16) | (uhi & 0xffff0000u);
}

// ---- stage 1 (one launch): bucket partial histograms + WT conv + x->bf16 conv ----
__global__ __launch_bounds__(256) void stage1_k(const int* __restrict__ dst,
                                                const float* __restrict__ x,
                                                const float* __restrict__ Wl,
                                                const float* __restrict__ Wr,
                                                int* __restrict__ partial,
                                                unsigned* __restrict__ hx2,
                                                unsigned short* __restrict__ WT,
                                                int nE, int nbuck, int ebB, int n2x) {
    if (blockIdx.x < (unsigned)ebB) {
        __shared__ int lh[NBUCK_MAX];
        for (int b = threadIdx.x; b < nbuck; b += 256) lh[b] = 0;
        __syncthreads();
        int base = blockIdx.x * EPB;
        int end = min(base + EPB, nE);
        for (int i = base + threadIdx.x; i < end; i += 256)
            atomicAdd(&lh[dst[i] >> BSHIFT], 1);
        __syncthreads();
        int* row = partial + (size_t)blockIdx.x * NBUCK_MAX;
        for (int b = threadIdx.x; b < nbuck; b += 256) row[b] = lh[b];
    } else if (blockIdx.x < (unsigned)(ebB + 384)) {
        int idx = (blockIdx.x - ebB) * 256 + threadIdx.x;    // < 3*128*256
        int l = idx / (128 * 256);
        int rem = idx % (128 * 256);
        int n = rem / 256;
        int k = rem % 256;
        float v = (k < 128) ? Wl[(size_t)l * 128 * 128 + (size_t)k * 128 + n]
                            : Wr[(size_t)l * 128 * 128 + (size_t)(k - 128) * 128 + n];
        WT[idx] = f2bf(v);
    } else {
        int i = (blockIdx.x - ebB - 384) * 256 + threadIdx.x;
        if (i < n2x) {
            float2 v = ((const float2*)x)[i];
            hx2[i] = pack_bf16x2(v.x, v.y);
        }
    }
}

// ---- stage 2a: per-bucket column scan over block partials (one block per bucket) ----
__global__ __launch_bounds__(256) void colscan_k(int* __restrict__ partial,
                                                 int* __restrict__ bucketTotal, int ebB) {
    int b = blockIdx.x;
    int t = threadIdx.x;
    const int CH = (ebB + 255) / 256;     // <= 8 for ebB <= 2048
    int vals[8];
    int s = 0;
    #pragma unroll
    for (int c = 0; c < 8; ++c) {
        if (c >= CH) break;
        int k = t * CH + c;
        int v = (k < ebB) ? partial[(size_t)k * NBUCK_MAX + b] : 0;
        vals[c] = v; s += v;
    }
    __shared__ int part[256];
    part[t] = s;
    __syncthreads();
    for (int d = 1; d < 256; d <<= 1) {
        int u = (t >= d) ? part[t - d] : 0;
        __syncthreads();
        if (t >= d) part[t] += u;
        __syncthreads();
    }
    int run = (t == 0) ? 0 : part[t - 1];
    #pragma unroll
    for (int c = 0; c < 8; ++c) {
        if (c >= CH) break;
        int k = t * CH + c;
        if (k < ebB) partial[(size_t)k * NBUCK_MAX + b] = run;
        run += vals[c];
    }
    if (t == 255) bucketTotal[b] = run;
}

// ---- stage 2b: scan bucket totals -> bucketStart (single block, small) ----
__global__ __launch_bounds__(512) void bscan2_k(const int* __restrict__ bucketTotal,
                                                int* __restrict__ bucketStart,
                                                int* __restrict__ row_ptr,
                                                int nbuck, int nE, int nN) {
    __shared__ int part[512];
    int t = threadIdx.x;
    int v = (t < nbuck) ? bucketTotal[t] : 0;
    part[t] = v;
    __syncthreads();
    for (int d = 1; d < 512; d <<= 1) {
        int u = (t >= d) ? part[t - d] : 0;
        __syncthreads();
        if (t >= d) part[t] += u;
        __syncthreads();
    }
    if (t < nbuck) bucketStart[t] = part[t] - v;
    if (t == 0) { bucketStart[nbuck] = nE; row_ptr[nN] = nE; }
}

// ---- stage 3: bucket placement, deterministic (base from partial prefix) ----
__global__ __launch_bounds__(256) void bplace_k(const int* __restrict__ src,
                                                const int* __restrict__ dst,
                                                const int* __restrict__ partial,
                                                const int* __restrict__ bucketStart,
                                                uint2* __restrict__ staged, int nE, int nbuck) {
    __shared__ int lh[NBUCK_MAX];
    __shared__ int lb[NBUCK_MAX];
    for (int b = threadIdx.x; b < nbuck; b += 256) lh[b] = 0;
    __syncthreads();
    int base = blockIdx.x * EPB;
    int end = min(base + EPB, nE);
    const int* myPre = partial + (size_t)blockIdx.x * NBUCK_MAX;
    for (int b = threadIdx.x; b < nbuck; b += 256)
        lb[b] = bucketStart[b] + myPre[b];
    __syncthreads();
    for (int i = base + threadIdx.x; i < end; i += 256) {
        int d = dst[i];
        int b = d >> BSHIFT;
        int loc = atomicAdd(&lh[b], 1);      // LDS-only cursor
        staged[lb[b] + loc] = make_uint2((unsigned)src[i], (unsigned)d);
    }
}

// ---- stage 4: per-bucket finish: counts -> row_ptr/inv, place csr_src (L2-local) ----
__global__ __launch_bounds__(256) void sort_bucket_k(const uint2* __restrict__ staged,
                                                     const int* __restrict__ bucketStart,
                                                     int* __restrict__ row_ptr,
                                                     float* __restrict__ inv,
                                                     int* __restrict__ csr_src, int nN) {
    __shared__ int cnt[128];
    __shared__ int rp[128];
    int g = blockIdx.x;
    int beg = bucketStart[g], end = bucketStart[g + 1];
    if (threadIdx.x < 128) cnt[threadIdx.x] = 0;
    __syncthreads();
    for (int i = beg + threadIdx.x; i < end; i += 256)
        atomicAdd(&cnt[staged[i].y & 127], 1);
    __syncthreads();
    if (threadIdx.x < 128) rp[threadIdx.x] = cnt[threadIdx.x];
    __syncthreads();
    #pragma unroll
    for (int d = 1; d < 128; d <<= 1) {
        int v = 0;
        if (threadIdx.x < 128 && threadIdx.x >= d) v = rp[threadIdx.x - d];
        __syncthreads();
        if (threadIdx.x < 128 && threadIdx.x >= d) rp[threadIdx.x] += v;
        __syncthreads();
    }
    if (threadIdx.x < 128) {
        int c = cnt[threadIdx.x];
        int excl = rp[threadIdx.x] - c;
        int node = (g << BSHIFT) + threadIdx.x;
        if (node < nN) {
            row_ptr[node] = beg + excl;
            inv[node] = 1.0f / fmaxf((float)c, 1.0f);
        }
        cnt[threadIdx.x] = excl;               // reuse as cursor
    }
    __syncthreads();
    for (int i = beg + threadIdx.x; i < end; i += 256) {
        uint2 e = staged[i];
        int pos = atomicAdd(&cnt[e.y & 127], 1);
        csr_src[beg + pos] = (int)e.x;
    }
}

// ---- fused layer: block = 16 nodes, 4 waves; wave gathers 4 nodes -> LDS mean;
//      barrier; MFMA 16 rows x 128 cols (wave: 32 cols), B from L2-hot WT.
//      12500 waves -> CU wave-cap occupancy (fixes R8's 12-waves/CU starvation). ----
__global__ __launch_bounds__(256) void sage_layer_k(
    const int* __restrict__ row_ptr,
    const int* __restrict__ csr_src,
    const float* __restrict__ inv,
    const uint4* __restrict__ h4,
    const unsigned short* __restrict__ h,
    const unsigned short* __restrict__ WT,   // [128][256] bf16
    const float* __restrict__ bl,
    unsigned short* __restrict__ out, int nN)
{
    __shared__ unsigned short meanS[16 * 128];   // 4 KB; 16B unit u of row r stored at u^r
    const int wave = threadIdx.x >> 6;
    const int lane = threadIdx.x & 63;
    const int quarter = lane >> 4;
    const int col = lane & 15;
    const int nb = blockIdx.x * 16;

    // ---- phase 1: gather means for 4 nodes (2-deep ILP, proven equal to 4-deep) ----
    for (int ii = 0; ii < 4; ++ii) {
        int i = wave * 4 + ii;                // local row 0..15
        int n = nb + i;
        float accA[8] = {}, accB[8] = {};
        if (n < nN) {
            int beg = row_ptr[n], end = row_ptr[n + 1];
            for (int base = beg; base < end; base += 64) {
                int navail = min(64, end - base);
                int idx = (lane < navail) ? csr_src[base + lane] : 0;
                for (int j = 0; j < navail; j += 8) {
                    int e0 = j + quarter;
                    int e1 = j + 4 + quarter;
                    int s0 = __shfl(idx, min(e0, navail - 1), 64);
                    int s1 = __shfl(idx, min(e1, navail - 1), 64);
                    uint4 u0 = h4[(size_t)s0 * 16 + col];
                    uint4 u1 = h4[(size_t)s1 * 16 + col];
                    if (e0 < navail) {
                        accA[0] += __uint_as_float(u0.x << 16); accA[1] += __uint_as_float(u0.x & 0xffff0000u);
                        accA[2] += __uint_as_float(u0.y << 16); accA[3] += __uint_as_float(u0.y & 0xffff0000u);
                        accA[4] += __uint_as_float(u0.z << 16); accA[5] += __uint_as_float(u0.z & 0xffff0000u);
                        accA[6] += __uint_as_float(u0.w << 16); accA[7] += __uint_as_float(u0.w & 0xffff0000u);
                    }
                    if (e1 < navail) {
                        accB[0] += __uint_as_float(u1.x << 16); accB[1] += __uint_as_float(u1.x & 0xffff0000u);
                        accB[2] += __uint_as_float(u1.y << 16); accB[3] += __uint_as_float(u1.y & 0xffff0000u);
                        accB[4] += __uint_as_float(u1.z << 16); accB[5] += __uint_as_float(u1.z & 0xffff0000u);
                        accB[6] += __uint_as_float(u1.w << 16); accB[7] += __uint_as_float(u1.w & 0xffff0000u);
                    }
                }
            }
        }
        #pragma unroll
        for (int k = 0; k < 8; ++k) {
            float v = accA[k] + accB[k];
            v += __shfl_xor(v, 16, 64);
            v += __shfl_xor(v, 32, 64);
            accA[k] = v;
        }
        if (quarter == 0) {
            float iv = inv[min(n, nN - 1)];
            uint4 o;
            o.x = pack_bf16x2(accA[0] * iv, accA[1] * iv);
            o.y = pack_bf16x2(accA[2] * iv, accA[3] * iv);
            o.z = pack_bf16x2(accA[4] * iv, accA[5] * iv);
            o.w = pack_bf16x2(accA[6] * iv, accA[7] * iv);
            *(uint4*)(meanS + i * 128 + ((col ^ i) & 15) * 8) = o;   // swizzle u^row
        }
    }
    __syncthreads();

    // ---- phase 2: MFMA; wave covers cols [wave*32, wave*32+32) ----
    const int m = col;
    const int q = quarter;
    const int rowc = min(nb + m, nN - 1);

    f32x4 acc[2] = {};
    #pragma unroll
    for (int ks = 0; ks < 8; ++ks) {
        short8 a;
        if (ks < 4) {
            int unit = ks * 4 + q;           // 0..15
            a = *(const short8*)(meanS + m * 128 + ((unit ^ m) & 15) * 8);
        } else {
            a = *(const short8*)(h + (size_t)rowc * HID + (ks - 4) * 32 + q * 8);
        }
        #pragma unroll
        for (int t = 0; t < 2; ++t) {
            int ncol = wave * 32 + t * 16 + m;
            short8 b = *(const short8*)(WT + (size_t)ncol * 256 + (ks * 4 + q) * 8);
            acc[t] = __builtin_amdgcn_mfma_f32_16x16x32_bf16(a, b, acc[t], 0, 0, 0);
        }
    }

    // C/D: col = lane&15 within tile, row = q*4 + reg
    #pragma unroll
    for (int t = 0; t < 2; ++t) {
        int ocol = wave * 32 + t * 16 + m;
        float bias = bl[ocol];
        #pragma unroll
        for (int r = 0; r < 4; ++r) {
            int orow = nb + q * 4 + r;
            if (orow < nN) {
                float v = fmaxf(acc[t][r] + bias, 0.f);
                out[(size_t)orow * HID + ocol] = f2bf(v);
            }
        }
    }
}

// ---------------- segmented pool (batch sorted): one block per graph ----------------
__global__ __launch_bounds__(256) void pool_seg_k(const unsigned* __restrict__ h2,
                                                  const int* __restrict__ batch,
                                                  float* __restrict__ pooled, int nN) {
    int g = blockIdx.x;
    int lo = 0, hi = nN;
    while (lo < hi) { int mid = (lo + hi) >> 1; if (batch[mid] < g) lo = mid + 1; else hi = mid; }
    int beg = lo;
    hi = nN;
    while (lo < hi) { int mid = (lo + hi) >> 1; if (batch[mid] <= g) lo = mid + 1; else hi = mid; }
    int end = lo;

    int lane = threadIdx.x & 63;
    int sub  = threadIdx.x >> 6;          // 4 waves
    float s0 = 0.f, s1 = 0.f;
    for (int i = beg + sub; i < end; i += 4) {
        unsigned u = h2[(size_t)i * 64 + lane];
        s0 += __uint_as_float(u << 16);
        s1 += __uint_as_float(u & 0xffff0000u);
    }
    __shared__ float red[4][HID];
    red[sub][2 * lane]     = s0;
    red[sub][2 * lane + 1] = s1;
    __syncthreads();
    if (sub == 0) {
        float v0 = red[0][2 * lane] + red[1][2 * lane] + red[2][2 * lane] + red[3][2 * lane];
        float v1 = red[0][2 * lane + 1] + red[1][2 * lane + 1] + red[2][2 * lane + 1] + red[3][2 * lane + 1];
        pooled[(size_t)g * HID + 2 * lane]     = v0;
        pooled[(size_t)g * HID + 2 * lane + 1] = v1;
    }
}

// ---------------- batchnorm stats: 1024 thr, 8 graph-stripes x 128 features ----------------
__global__ __launch_bounds__(1024) void bn_stats_k(const float* __restrict__ pooled,
                                                   const float* __restrict__ gamma,
                                                   const float* __restrict__ beta,
                                                   float* __restrict__ scale,
                                                   float* __restrict__ shift, int nG) {
    __shared__ float rs[8][HID], rs2[8][HID];
    int j = threadIdx.x & (HID - 1);
    int stripe = threadIdx.x >> 7;         // 0..7
    float s = 0.f, s2 = 0.f;
    for (int g = stripe; g < nG; g += 8) {
        float v = pooled[(size_t)g * HID + j];
        s += v; s2 += v * v;
    }
    rs[stripe][j] = s; rs2[stripe][j] = s2;
    __syncthreads();
    if (threadIdx.x < HID) {
        float S = 0.f, S2 = 0.f;
        #pragma unroll
        for (int k = 0; k < 8; ++k) { S += rs[k][j]; S2 += rs2[k][j]; }
        float invG = 1.0f / (float)nG;
        float mu = S * invG;
        float var = S2 * invG - mu * mu;
        float r = rsqrtf(var + 1e-5f) * gamma[j];
        scale[j] = r;
        shift[j] = beta[j] - mu * r;
    }
}

// ---------------- final FC ----------------
__global__ __launch_bounds__(LATENT) void fc_k(const float* __restrict__ pooled,
                                               const float* __restrict__ scale,
                                               const float* __restrict__ shift,
                                               const float* __restrict__ fcW,
                                               const float* __restrict__ fcb,
                                               float* __restrict__ out, int nG) {
    int g = blockIdx.x;
    int o = threadIdx.x;
    float acc = fcb[o];
    for (int j = 0; j < HID; ++j) {
        float v = pooled[(size_t)g * HID + j] * scale[j] + shift[j];
        acc += v * fcW[(size_t)j * LATENT + o];
    }
    out[(size_t)g * LATENT + o] = acc;
}

extern "C" void kernel_launch(void* const* d_in, const int* in_sizes, int n_in,
                              void* d_out, int out_size, void* d_ws, size_t ws_size,
                              hipStream_t stream) {
    const float* x     = (const float*)d_in[0];
    const int*   ei    = (const int*)d_in[1];
    const int*   batch = (const int*)d_in[2];
    const float* Wl    = (const float*)d_in[3];
    const float* bl    = (const float*)d_in[4];
    const float* Wr    = (const float*)d_in[5];
    const float* gamma = (const float*)d_in[6];
    const float* beta  = (const float*)d_in[7];
    const float* fcW   = (const float*)d_in[8];
    const float* fcb   = (const float*)d_in[9];
    float* out = (float*)d_out;

    const int nN = in_sizes[0] / HID;      // 50000
    const int nE = in_sizes[1] / 2;        // 800000
    const int nG = out_size / LATENT;      // 256
    const int* src = ei;
    const int* dst = ei + nE;
    const int nbuck = (nN + 127) >> BSHIFT;   // 391
    const int ebB = (nE + EPB - 1) / EPB;     // 782

    unsigned short* hx   = (unsigned short*)d_ws;           // nN*HID bf16
    unsigned short* B1   = hx + (size_t)nN * HID;
    unsigned short* B2   = B1 + (size_t)nN * HID;
    unsigned short* spare= B2 + (size_t)nN * HID;           // staged aliases here
    unsigned short* WT   = spare + (size_t)nN * HID;        // 3*128*256 bf16
    float* inv    = (float*)(WT + 3 * 128 * 256);
    float* pooled = inv + nN;
    float* scale  = pooled + (size_t)nG * HID;
    float* shift  = scale + HID;
    int*   row_ptr     = (int*)(shift + HID);               // nN+1
    int*   csr_src     = row_ptr + (nN + 1);
    int*   bucketStart = csr_src + nE;                      // nbuck+1
    int*   bucketTotal = bucketStart + NBUCK_MAX + 1;
    int*   partial     = bucketTotal + NBUCK_MAX;           // ebB*NBUCK_MAX ints
    uint2* staged      = (uint2*)spare;                     // 6.4 MB <= 12.8 MB slot

    const int n2x = nN * HID / 2;
    const int convx_blocks = (n2x + 255) / 256;

    // ---- CSR build + conversions: 5 launches, zero global atomics, no memset ----
    stage1_k<<<ebB + 384 + convx_blocks, 256, 0, stream>>>(dst, x, Wl, Wr, partial,
                                                           (unsigned*)hx, WT, nE, nbuck, ebB, n2x);
    colscan_k<<<nbuck, 256, 0, stream>>>(partial, bucketTotal, ebB);
    bscan2_k<<<1, 512, 0, stream>>>(bucketTotal, bucketStart, row_ptr, nbuck, nE, nN);
    bplace_k<<<ebB, 256, 0, stream>>>(src, dst, partial, bucketStart, staged, nE, nbuck);
    sort_bucket_k<<<nbuck, 256, 0, stream>>>(staged, bucketStart, row_ptr, inv, csr_src, nN);

    const int layer_blocks = (nN + 15) / 16;

    const unsigned short* hcur = hx;
    unsigned short* outs[3] = {B1, B2, B1};
    for (int l = 0; l < 3; ++l) {
        sage_layer_k<<<layer_blocks, 256, 0, stream>>>(row_ptr, csr_src, inv,
                                                       (const uint4*)hcur, hcur,
                                                       WT + (size_t)l * 128 * 256,
                                                       bl + (size_t)l * HID,
                                                       outs[l], nN);
        hcur = outs[l];
    }

    pool_seg_k<<<nG, 256, 0, stream>>>((const unsigned*)hcur, batch, pooled, nN);
    bn_stats_k<<<1, 1024, 0, stream>>>(pooled, gamma, beta, scale, shift, nG);
    fc_k<<<nG, LATENT, 0, stream>>>(pooled, scale, shift, fcW, fcb, out, nG);
}

// Round 16
// 314.620 us; speedup vs baseline: 1.0578x; 1.0578x over previous
//
#include <hip/hip_runtime.h>
#include <cstdint>
#include <cstddef>

constexpr int HID = 128;
constexpr int LATENT = 64;
constexpr int BSHIFT = 7;           // 128 nodes per bucket
constexpr int NBUCK_MAX = 512;      // supports up to 65536 nodes
constexpr int EPB = 1024;           // edges per block in bucket passes

typedef __attribute__((ext_vector_type(8))) short short8;
typedef __attribute__((ext_vector_type(4))) float f32x4;

__device__ inline unsigned short f2bf(float f) {
    unsigned u = __float_as_uint(f);
    u += 0x7fff + ((u >> 16) & 1);          // RNE
    return (unsigned short)(u >> 16);
}
__device__ inline unsigned pack_bf16x2(float lo, float hi) {
    unsigned ulo = __float_as_uint(lo);
    unsigned uhi = __float_as_uint(hi);
    ulo += 0x7fff + ((ulo >> 16) & 1);
    uhi += 0x7fff + ((uhi >> 16) & 1);
    return (ulo >> 16) | (uhi & 0xffff0000u);
}

// ---- stage 1 (one launch): bucket partial histograms + WT conv + x->bf16 conv ----
__global__ __launch_bounds__(256) void stage1_k(const int* __restrict__ dst,
                                                const float* __restrict__ x,
                                                const float* __restrict__ Wl,
                                                const float* __restrict__ Wr,
                                                int* __restrict__ partial,
                                                unsigned* __restrict__ hx2,
                                                unsigned short* __restrict__ WT,
                                                int nE, int nbuck, int ebB, int n2x) {
    if (blockIdx.x < (unsigned)ebB) {
        __shared__ int lh[NBUCK_MAX];
        for (int b = threadIdx.x; b < nbuck; b += 256) lh[b] = 0;
        __syncthreads();
        int base = blockIdx.x * EPB;
        int end = min(base + EPB, nE);
        for (int i = base + threadIdx.x; i < end; i += 256)
            atomicAdd(&lh[dst[i] >> BSHIFT], 1);
        __syncthreads();
        int* row = partial + (size_t)blockIdx.x * NBUCK_MAX;
        for (int b = threadIdx.x; b < nbuck; b += 256) row[b] = lh[b];
    } else if (blockIdx.x < (unsigned)(ebB + 384)) {
        int idx = (blockIdx.x - ebB) * 256 + threadIdx.x;    // < 3*128*256
        int l = idx / (128 * 256);
        int rem = idx % (128 * 256);
        int n = rem / 256;
        int k = rem % 256;
        float v = (k < 128) ? Wl[(size_t)l * 128 * 128 + (size_t)k * 128 + n]
                            : Wr[(size_t)l * 128 * 128 + (size_t)(k - 128) * 128 + n];
        WT[idx] = f2bf(v);
    } else {
        int i = (blockIdx.x - ebB - 384) * 256 + threadIdx.x;
        if (i < n2x) {
            float2 v = ((const float2*)x)[i];
            hx2[i] = pack_bf16x2(v.x, v.y);
        }
    }
}

// ---- stage 2a: per-bucket column scan over block partials (one block per bucket) ----
__global__ __launch_bounds__(256) void colscan_k(int* __restrict__ partial,
                                                 int* __restrict__ bucketTotal, int ebB) {
    int b = blockIdx.x;
    int t = threadIdx.x;
    const int CH = (ebB + 255) / 256;     // <= 8 for ebB <= 2048
    int vals[8];
    int s = 0;
    #pragma unroll
    for (int c = 0; c < 8; ++c) {
        if (c >= CH) break;
        int k = t * CH + c;
        int v = (k < ebB) ? partial[(size_t)k * NBUCK_MAX + b] : 0;
        vals[c] = v; s += v;
    }
    __shared__ int part[256];
    part[t] = s;
    __syncthreads();
    for (int d = 1; d < 256; d <<= 1) {
        int u = (t >= d) ? part[t - d] : 0;
        __syncthreads();
        if (t >= d) part[t] += u;
        __syncthreads();
    }
    int run = (t == 0) ? 0 : part[t - 1];
    #pragma unroll
    for (int c = 0; c < 8; ++c) {
        if (c >= CH) break;
        int k = t * CH + c;
        if (k < ebB) partial[(size_t)k * NBUCK_MAX + b] = run;
        run += vals[c];
    }
    if (t == 255) bucketTotal[b] = run;
}

// ---- stage 2b: scan bucket totals -> bucketStart (single block, small) ----
__global__ __launch_bounds__(512) void bscan2_k(const int* __restrict__ bucketTotal,
                                                int* __restrict__ bucketStart,
                                                int* __restrict__ row_ptr,
                                                int nbuck, int nE, int nN) {
    __shared__ int part[512];
    int t = threadIdx.x;
    int v = (t < nbuck) ? bucketTotal[t] : 0;
    part[t] = v;
    __syncthreads();
    for (int d = 1; d < 512; d <<= 1) {
        int u = (t >= d) ? part[t - d] : 0;
        __syncthreads();
        if (t >= d) part[t] += u;
        __syncthreads();
    }
    if (t < nbuck) bucketStart[t] = part[t] - v;
    if (t == 0) { bucketStart[nbuck] = nE; row_ptr[nN] = nE; }
}

// ---- stage 3: bucket placement, deterministic (base from partial prefix) ----
__global__ __launch_bounds__(256) void bplace_k(const int* __restrict__ src,
                                                const int* __restrict__ dst,
                                                const int* __restrict__ partial,
                                                const int* __restrict__ bucketStart,
                                                uint2* __restrict__ staged, int nE, int nbuck) {
    __shared__ int lh[NBUCK_MAX];
    __shared__ int lb[NBUCK_MAX];
    for (int b = threadIdx.x; b < nbuck; b += 256) lh[b] = 0;
    __syncthreads();
    int base = blockIdx.x * EPB;
    int end = min(base + EPB, nE);
    const int* myPre = partial + (size_t)blockIdx.x * NBUCK_MAX;
    for (int b = threadIdx.x; b < nbuck; b += 256)
        lb[b] = bucketStart[b] + myPre[b];
    __syncthreads();
    for (int i = base + threadIdx.x; i < end; i += 256) {
        int d = dst[i];
        int b = d >> BSHIFT;
        int loc = atomicAdd(&lh[b], 1);      // LDS-only cursor
        staged[lb[b] + loc] = make_uint2((unsigned)src[i], (unsigned)d);
    }
}

// ---- stage 4: per-bucket finish: counts -> row_ptr/inv, place csr_src (L2-local) ----
__global__ __launch_bounds__(256) void sort_bucket_k(const uint2* __restrict__ staged,
                                                     const int* __restrict__ bucketStart,
                                                     int* __restrict__ row_ptr,
                                                     float* __restrict__ inv,
                                                     int* __restrict__ csr_src, int nN) {
    __shared__ int cnt[128];
    __shared__ int rp[128];
    int g = blockIdx.x;
    int beg = bucketStart[g], end = bucketStart[g + 1];
    if (threadIdx.x < 128) cnt[threadIdx.x] = 0;
    __syncthreads();
    for (int i = beg + threadIdx.x; i < end; i += 256)
        atomicAdd(&cnt[staged[i].y & 127], 1);
    __syncthreads();
    if (threadIdx.x < 128) rp[threadIdx.x] = cnt[threadIdx.x];
    __syncthreads();
    #pragma unroll
    for (int d = 1; d < 128; d <<= 1) {
        int v = 0;
        if (threadIdx.x < 128 && threadIdx.x >= d) v = rp[threadIdx.x - d];
        __syncthreads();
        if (threadIdx.x < 128 && threadIdx.x >= d) rp[threadIdx.x] += v;
        __syncthreads();
    }
    if (threadIdx.x < 128) {
        int c = cnt[threadIdx.x];
        int excl = rp[threadIdx.x] - c;
        int node = (g << BSHIFT) + threadIdx.x;
        if (node < nN) {
            row_ptr[node] = beg + excl;
            inv[node] = 1.0f / fmaxf((float)c, 1.0f);
        }
        cnt[threadIdx.x] = excl;               // reuse as cursor
    }
    __syncthreads();
    for (int i = beg + threadIdx.x; i < end; i += 256) {
        uint2 e = staged[i];
        int pos = atomicAdd(&cnt[e.y & 127], 1);
        csr_src[beg + pos] = (int)e.x;
    }
}

// ---------------- pull-gather mean: uint4 loads, 16 lanes/row, 4-deep ILP ----------------
__global__ __launch_bounds__(256) void gather_k(const int* __restrict__ row_ptr,
                                                const int* __restrict__ csr_src,
                                                const float* __restrict__ inv,
                                                const uint4* __restrict__ h4,
                                                uint4* __restrict__ mean4, int nN) {
    int w = blockIdx.x * 4 + (threadIdx.x >> 6);
    if (w >= nN) return;
    int lane = threadIdx.x & 63;
    int quarter = lane >> 4;
    int col = lane & 15;
    int beg = row_ptr[w], end = row_ptr[w + 1];
    float accA[8] = {}, accB[8] = {}, accC[8] = {}, accD[8] = {};
    for (int base = beg; base < end; base += 64) {
        int navail = min(64, end - base);
        int idx = (lane < navail) ? csr_src[base + lane] : 0;
        for (int j = 0; j < navail; j += 16) {
            int e0 = j + quarter;
            int e1 = j + 4 + quarter;
            int e2 = j + 8 + quarter;
            int e3 = j + 12 + quarter;
            int s0 = __shfl(idx, min(e0, navail - 1), 64);
            int s1 = __shfl(idx, min(e1, navail - 1), 64);
            int s2 = __shfl(idx, min(e2, navail - 1), 64);
            int s3 = __shfl(idx, min(e3, navail - 1), 64);
            uint4 u0 = h4[(size_t)s0 * 16 + col];
            uint4 u1 = h4[(size_t)s1 * 16 + col];
            uint4 u2 = h4[(size_t)s2 * 16 + col];
            uint4 u3 = h4[(size_t)s3 * 16 + col];
            if (e0 < navail) {
                accA[0] += __uint_as_float(u0.x << 16); accA[1] += __uint_as_float(u0.x & 0xffff0000u);
                accA[2] += __uint_as_float(u0.y << 16); accA[3] += __uint_as_float(u0.y & 0xffff0000u);
                accA[4] += __uint_as_float(u0.z << 16); accA[5] += __uint_as_float(u0.z & 0xffff0000u);
                accA[6] += __uint_as_float(u0.w << 16); accA[7] += __uint_as_float(u0.w & 0xffff0000u);
            }
            if (e1 < navail) {
                accB[0] += __uint_as_float(u1.x << 16); accB[1] += __uint_as_float(u1.x & 0xffff0000u);
                accB[2] += __uint_as_float(u1.y << 16); accB[3] += __uint_as_float(u1.y & 0xffff0000u);
                accB[4] += __uint_as_float(u1.z << 16); accB[5] += __uint_as_float(u1.z & 0xffff0000u);
                accB[6] += __uint_as_float(u1.w << 16); accB[7] += __uint_as_float(u1.w & 0xffff0000u);
            }
            if (e2 < navail) {
                accC[0] += __uint_as_float(u2.x << 16); accC[1] += __uint_as_float(u2.x & 0xffff0000u);
                accC[2] += __uint_as_float(u2.y << 16); accC[3] += __uint_as_float(u2.y & 0xffff0000u);
                accC[4] += __uint_as_float(u2.z << 16); accC[5] += __uint_as_float(u2.z & 0xffff0000u);
                accC[6] += __uint_as_float(u2.w << 16); accC[7] += __uint_as_float(u2.w & 0xffff0000u);
            }
            if (e3 < navail) {
                accD[0] += __uint_as_float(u3.x << 16); accD[1] += __uint_as_float(u3.x & 0xffff0000u);
                accD[2] += __uint_as_float(u3.y << 16); accD[3] += __uint_as_float(u3.y & 0xffff0000u);
                accD[4] += __uint_as_float(u3.z << 16); accD[5] += __uint_as_float(u3.z & 0xffff0000u);
                accD[6] += __uint_as_float(u3.w << 16); accD[7] += __uint_as_float(u3.w & 0xffff0000u);
            }
        }
    }
    #pragma unroll
    for (int k = 0; k < 8; ++k) {
        float v = (accA[k] + accB[k]) + (accC[k] + accD[k]);
        v += __shfl_xor(v, 16, 64);
        v += __shfl_xor(v, 32, 64);
        accA[k] = v;
    }
    if (quarter == 0) {
        float iv = inv[w];
        uint4 o;
        o.x = pack_bf16x2(accA[0] * iv, accA[1] * iv);
        o.y = pack_bf16x2(accA[2] * iv, accA[3] * iv);
        o.z = pack_bf16x2(accA[4] * iv, accA[5] * iv);
        o.w = pack_bf16x2(accA[6] * iv, accA[7] * iv);
        mean4[(size_t)w * 16 + col] = o;
    }
}

// ---------------- MFMA SAGE transform: out = relu([mean|h] @ WT^T + bl), bf16 ----------------
__global__ __launch_bounds__(256) void sage_mfma_k(
    const unsigned short* __restrict__ mean,
    const unsigned short* __restrict__ h,
    const unsigned short* __restrict__ WT,   // [128][256] bf16
    const float* __restrict__ bl,
    unsigned short* __restrict__ out, int nN)
{
    __shared__ unsigned short sB[128 * 256];   // exactly 64 KB

    {
        int row = threadIdx.x >> 1, half = threadIdx.x & 1;
        const short8* src = (const short8*)(WT + row * 256 + half * 128);
        int sw = (row & 7) << 2;
        #pragma unroll
        for (int j = 0; j < 16; ++j) {
            int unit = half * 16 + j;
            int unit2 = unit ^ sw;
            *(short8*)(sB + row * 256 + unit2 * 8) = src[j];
        }
    }
    __syncthreads();

    const int wave = threadIdx.x >> 6;
    const int lane = threadIdx.x & 63;
    const int m = lane & 15;
    const int q = lane >> 4;
    const int row = blockIdx.x * 64 + wave * 16 + m;
    const int rowc = min(row, nN - 1);
    const int swm = (m & 7) << 2;

    f32x4 acc[8] = {};
    #pragma unroll
    for (int ks = 0; ks < 8; ++ks) {
        const unsigned short* Aptr = (ks < 4) ? mean : h;
        short8 a = *(const short8*)(Aptr + (size_t)rowc * HID + (ks & 3) * 32 + q * 8);
        #pragma unroll
        for (int t = 0; t < 8; ++t) {
            int unit2 = (ks * 4 + q) ^ swm;
            short8 b = *(const short8*)(sB + (t * 16 + m) * 256 + unit2 * 8);
            acc[t] = __builtin_amdgcn_mfma_f32_16x16x32_bf16(a, b, acc[t], 0, 0, 0);
        }
    }

    int orow_base = blockIdx.x * 64 + wave * 16 + q * 4;
    #pragma unroll
    for (int t = 0; t < 8; ++t) {
        float bias = bl[t * 16 + m];
        #pragma unroll
        for (int r = 0; r < 4; ++r) {
            int orow = orow_base + r;
            if (orow < nN) {
                float v = fmaxf(acc[t][r] + bias, 0.f);
                out[(size_t)orow * HID + t * 16 + m] = f2bf(v);
            }
        }
    }
}

// ---------------- segmented pool (batch sorted): one block per graph ----------------
__global__ __launch_bounds__(256) void pool_seg_k(const unsigned* __restrict__ h2,
                                                  const int* __restrict__ batch,
                                                  float* __restrict__ pooled, int nN) {
    int g = blockIdx.x;
    int lo = 0, hi = nN;
    while (lo < hi) { int mid = (lo + hi) >> 1; if (batch[mid] < g) lo = mid + 1; else hi = mid; }
    int beg = lo;
    hi = nN;
    while (lo < hi) { int mid = (lo + hi) >> 1; if (batch[mid] <= g) lo = mid + 1; else hi = mid; }
    int end = lo;

    int lane = threadIdx.x & 63;
    int sub  = threadIdx.x >> 6;          // 4 waves
    float s0 = 0.f, s1 = 0.f;
    for (int i = beg + sub; i < end; i += 4) {
        unsigned u = h2[(size_t)i * 64 + lane];
        s0 += __uint_as_float(u << 16);
        s1 += __uint_as_float(u & 0xffff0000u);
    }
    __shared__ float red[4][HID];
    red[sub][2 * lane]     = s0;
    red[sub][2 * lane + 1] = s1;
    __syncthreads();
    if (sub == 0) {
        float v0 = red[0][2 * lane] + red[1][2 * lane] + red[2][2 * lane] + red[3][2 * lane];
        float v1 = red[0][2 * lane + 1] + red[1][2 * lane + 1] + red[2][2 * lane + 1] + red[3][2 * lane + 1];
        pooled[(size_t)g * HID + 2 * lane]     = v0;
        pooled[(size_t)g * HID + 2 * lane + 1] = v1;
    }
}

// ---------------- batchnorm stats: 1024 thr, 8 graph-stripes x 128 features ----------------
__global__ __launch_bounds__(1024) void bn_stats_k(const float* __restrict__ pooled,
                                                   const float* __restrict__ gamma,
                                                   const float* __restrict__ beta,
                                                   float* __restrict__ scale,
                                                   float* __restrict__ shift, int nG) {
    __shared__ float rs[8][HID], rs2[8][HID];
    int j = threadIdx.x & (HID - 1);
    int stripe = threadIdx.x >> 7;         // 0..7
    float s = 0.f, s2 = 0.f;
    for (int g = stripe; g < nG; g += 8) {
        float v = pooled[(size_t)g * HID + j];
        s += v; s2 += v * v;
    }
    rs[stripe][j] = s; rs2[stripe][j] = s2;
    __syncthreads();
    if (threadIdx.x < HID) {
        float S = 0.f, S2 = 0.f;
        #pragma unroll
        for (int k = 0; k < 8; ++k) { S += rs[k][j]; S2 += rs2[k][j]; }
        float invG = 1.0f / (float)nG;
        float mu = S * invG;
        float var = S2 * invG - mu * mu;
        float r = rsqrtf(var + 1e-5f) * gamma[j];
        scale[j] = r;
        shift[j] = beta[j] - mu * r;
    }
}

// ---------------- final FC ----------------
__global__ __launch_bounds__(LATENT) void fc_k(const float* __restrict__ pooled,
                                               const float* __restrict__ scale,
                                               const float* __restrict__ shift,
                                               const float* __restrict__ fcW,
                                               const float* __restrict__ fcb,
                                               float* __restrict__ out, int nG) {
    int g = blockIdx.x;
    int o = threadIdx.x;
    float acc = fcb[o];
    for (int j = 0; j < HID; ++j) {
        float v = pooled[(size_t)g * HID + j] * scale[j] + shift[j];
        acc += v * fcW[(size_t)j * LATENT + o];
    }
    out[(size_t)g * LATENT + o] = acc;
}

extern "C" void kernel_launch(void* const* d_in, const int* in_sizes, int n_in,
                              void* d_out, int out_size, void* d_ws, size_t ws_size,
                              hipStream_t stream) {
    const float* x     = (const float*)d_in[0];
    const int*   ei    = (const int*)d_in[1];
    const int*   batch = (const int*)d_in[2];
    const float* Wl    = (const float*)d_in[3];
    const float* bl    = (const float*)d_in[4];
    const float* Wr    = (const float*)d_in[5];
    const float* gamma = (const float*)d_in[6];
    const float* beta  = (const float*)d_in[7];
    const float* fcW   = (const float*)d_in[8];
    const float* fcb   = (const float*)d_in[9];
    float* out = (float*)d_out;

    const int nN = in_sizes[0] / HID;      // 50000
    const int nE = in_sizes[1] / 2;        // 800000
    const int nG = out_size / LATENT;      // 256
    const int* src = ei;
    const int* dst = ei + nE;
    const int nbuck = (nN + 127) >> BSHIFT;   // 391
    const int ebB = (nE + EPB - 1) / EPB;     // 782

    unsigned short* hx   = (unsigned short*)d_ws;           // nN*HID bf16
    unsigned short* B1   = hx + (size_t)nN * HID;
    unsigned short* B2   = B1 + (size_t)nN * HID;
    unsigned short* mean = B2 + (size_t)nN * HID;           // aliased by staged
    unsigned short* WT   = mean + (size_t)nN * HID;         // 3*128*256 bf16
    float* inv    = (float*)(WT + 3 * 128 * 256);
    float* pooled = inv + nN;
    float* scale  = pooled + (size_t)nG * HID;
    float* shift  = scale + HID;
    int*   row_ptr     = (int*)(shift + HID);               // nN+1
    int*   csr_src     = row_ptr + (nN + 1);
    int*   bucketStart = csr_src + nE;                      // nbuck+1
    int*   bucketTotal = bucketStart + NBUCK_MAX + 1;
    int*   partial     = bucketTotal + NBUCK_MAX;           // ebB*NBUCK_MAX ints
    uint2* staged      = (uint2*)mean;                      // 6.4 MB <= mean's 12.8 MB

    const int n2x = nN * HID / 2;
    const int convx_blocks = (n2x + 255) / 256;

    // ---- CSR build + conversions: 5 launches, zero global atomics, no memset ----
    stage1_k<<<ebB + 384 + convx_blocks, 256, 0, stream>>>(dst, x, Wl, Wr, partial,
                                                           (unsigned*)hx, WT, nE, nbuck, ebB, n2x);
    colscan_k<<<nbuck, 256, 0, stream>>>(partial, bucketTotal, ebB);
    bscan2_k<<<1, 512, 0, stream>>>(bucketTotal, bucketStart, row_ptr, nbuck, nE, nN);
    bplace_k<<<ebB, 256, 0, stream>>>(src, dst, partial, bucketStart, staged, nE, nbuck);
    sort_bucket_k<<<nbuck, 256, 0, stream>>>(staged, bucketStart, row_ptr, inv, csr_src, nN);

    const int gather_blocks = (nN + 3) / 4;
    const int gemm_blocks = (nN + 63) / 64;

    const unsigned short* hcur = hx;
    unsigned short* outs[3] = {B1, B2, B1};
    for (int l = 0; l < 3; ++l) {
        gather_k<<<gather_blocks, 256, 0, stream>>>(row_ptr, csr_src, inv,
                                                    (const uint4*)hcur, (uint4*)mean, nN);
        sage_mfma_k<<<gemm_blocks, 256, 0, stream>>>(mean, hcur,
                                                     WT + (size_t)l * 128 * 256,
                                                     bl + (size_t)l * HID,
                                                     outs[l], nN);
        hcur = outs[l];
    }

    pool_seg_k<<<nG, 256, 0, stream>>>((const unsigned*)hcur, batch, pooled, nN);
    bn_stats_k<<<1, 1024, 0, stream>>>(pooled, gamma, beta, scale, shift, nG);
    fc_k<<<nG, LATENT, 0, stream>>>(pooled, scale, shift, fcW, fcb, out, nG);
}